// Round 2
// baseline (224.512 us; speedup 1.0000x reference)
//
#include <hip/hip_runtime.h>
#include <hip/hip_bf16.h>
#include <math.h>

typedef __bf16 bf16;
typedef __bf16 bf16x4 __attribute__((ext_vector_type(4)));
typedef __bf16 bf16x8 __attribute__((ext_vector_type(8)));
typedef float f32x4 __attribute__((ext_vector_type(4)));

#define NB 4
#define NN 1024
#define ND 256
#define NH 8
#define INFV 1e38f

__device__ __forceinline__ f32x4 mfma16(bf16x8 a, bf16x8 b, f32x4 c) {
    return __builtin_amdgcn_mfma_f32_16x16x32_bf16(a, b, c, 0, 0, 0);
}

// C = A(Mx256) @ W(256x128-tile) + bias, MODE0: store f32 + bf16; MODE1: out = add + relu(C)
template<int MODE>
__global__ __launch_bounds__(256)
void gemm_k(const float* __restrict__ A,
            const float* __restrict__ W0, const float* __restrict__ b0,
            const float* __restrict__ W1, const float* __restrict__ b1,
            const float* __restrict__ W2, const float* __restrict__ b2,
            float* __restrict__ F0, bf16* __restrict__ G0,
            float* __restrict__ F1, bf16* __restrict__ G1,
            float* __restrict__ F2, bf16* __restrict__ G2,
            const float* __restrict__ addsrc)
{
    const int z = blockIdx.z;
    const float* W    = (z == 0) ? W0 : (z == 1) ? W1 : W2;
    const float* bias = (z == 0) ? b0 : (z == 1) ? b1 : b2;
    float* Fo = (z == 0) ? F0 : (z == 1) ? F1 : F2;
    bf16*  Go = (z == 0) ? G0 : (z == 1) ? G1 : G2;

    const int brow = blockIdx.x * 128;
    const int bcol = blockIdx.y * 128;
    const int t    = threadIdx.x;
    const int lane = t & 63;
    const int wv   = t >> 6;
    const int g    = lane >> 4;
    const int l16  = lane & 15;

    __shared__ bf16 As[128][40];   // [row][k] bf16, 80B rows (16B aligned)
    __shared__ bf16 Wt[128][40];   // [col][k] bf16 (transposed W tile)

    f32x4 acc[2][8];
    #pragma unroll
    for (int i = 0; i < 2; ++i)
        #pragma unroll
        for (int j = 0; j < 8; ++j) acc[i][j] = f32x4{0.f, 0.f, 0.f, 0.f};

    for (int k0 = 0; k0 < 256; k0 += 32) {
        // stage A tile 128x32 (f32 -> bf16)
        {
            const int r = t >> 3, j = t & 7;
            #pragma unroll
            for (int p = 0; p < 4; ++p) {
                const float4 v = *(const float4*)&A[(size_t)(brow + r + 32*p)*ND + k0 + 4*j];
                bf16x4 w4 = { (bf16)v.x, (bf16)v.y, (bf16)v.z, (bf16)v.w };
                *(bf16x4*)&As[r + 32*p][4*j] = w4;
            }
        }
        // stage W tile 32x128 transposed -> Wt[col][k]
        {
            const int c = t & 127, kk = t >> 7;  // kk in {0,1}
            #pragma unroll
            for (int p = 0; p < 16; ++p) {
                const int k = kk*16 + p;
                Wt[c][k] = (bf16)W[(size_t)(k0 + k)*ND + bcol + c];
            }
        }
        __syncthreads();

        bf16x8 af[2];
        #pragma unroll
        for (int i = 0; i < 2; ++i)
            af[i] = *(const bf16x8*)&As[wv*32 + i*16 + l16][8*g];
        #pragma unroll
        for (int j = 0; j < 8; ++j) {
            const bf16x8 bfj = *(const bf16x8*)&Wt[j*16 + l16][8*g];
            #pragma unroll
            for (int i = 0; i < 2; ++i) acc[i][j] = mfma16(af[i], bfj, acc[i][j]);
        }
        __syncthreads();
    }

    // epilogue: D layout col = lane&15, row = 4*(lane>>4)+reg  [HW-verified]
    #pragma unroll
    for (int j = 0; j < 8; ++j) {
        const int col = bcol + j*16 + l16;
        const float bj = bias[col];
        #pragma unroll
        for (int i = 0; i < 2; ++i) {
            #pragma unroll
            for (int r = 0; r < 4; ++r) {
                const int row = brow + wv*32 + i*16 + 4*g + r;
                const size_t idx = (size_t)row*ND + col;
                float v = acc[i][j][r] + bj;
                if (MODE == 1) {
                    Fo[idx] = addsrc[idx] + fmaxf(v, 0.f);
                } else {
                    Fo[idx] = v;
                    Go[idx] = (bf16)v;
                }
            }
        }
    }
}

// Fused attention: per block = (batch b, 16 q-rows), 8 waves = 8 heads.
// Online softmax over 32-key tiles; loc gate computed in MFMA C-layout.
__global__ __launch_bounds__(512)
void attn_k(const bf16* __restrict__ Qb, const bf16* __restrict__ Kb,
            const bf16* __restrict__ Vb, const float* __restrict__ Vf,
            const float* __restrict__ Xpg,
            const float* __restrict__ prq, const float* __restrict__ prk,
            const float* __restrict__ Wg1, const float* __restrict__ bg1,
            const float* __restrict__ wg2, const float* __restrict__ bg2,
            float* __restrict__ O1)
{
    const int b    = blockIdx.y;
    const int q0   = blockIdx.x * 16;
    const int t    = threadIdx.x;
    const int w    = t >> 6;       // wave id == head
    const int lane = t & 63;
    const int g    = lane >> 4;
    const int l16  = lane & 15;

    __shared__ bf16  Qs[16][264];      // [q][d] bf16
    __shared__ bf16  Ks[32][264];      // [m][d] bf16
    __shared__ bf16  Vst[256][40];     // [d][m-swizzled] bf16 (transposed V tile)
    __shared__ float Xps[16*32*4];     // [q][m][4] f32 (stride-4 for b128 reads)
    __shared__ bf16  Ps[8][16][40];    // wave-private P tiles [q][m]
    __shared__ float pqs[16];
    __shared__ float pks[32];

    // head gate weights (wave-uniform)
    float g1[3][3], gb1[3], g2v[3], gb2v;
    #pragma unroll
    for (int c = 0; c < 3; ++c)
        #pragma unroll
        for (int d = 0; d < 3; ++d) g1[c][d] = Wg1[(w*3 + c)*3 + d];
    #pragma unroll
    for (int d = 0; d < 3; ++d) { gb1[d] = bg1[w*3 + d]; g2v[d] = wg2[w*3 + d]; }
    gb2v = bg2[w];

    // stage Q (16x256 bf16) + presence_q
    for (int i = t; i < 16*64; i += 512) {
        const int q = i >> 6, j = i & 63;
        *(bf16x4*)&Qs[q][4*j] = *(const bf16x4*)&Qb[((size_t)b*NN + q0 + q)*ND + 4*j];
    }
    if (t < 16) pqs[t] = prq[b*NN + q0 + t];
    __syncthreads();

    // A-fragment of Q for this head (row = l16, k = 8g..8g+7 within head slice)
    const bf16x8 qf = *(const bf16x8*)&Qs[l16][w*32 + 8*g];

    float m_run[4], l_run[4];
    f32x4 oh[2];
    #pragma unroll
    for (int r = 0; r < 4; ++r) { m_run[r] = -INFINITY; l_run[r] = 0.f; }
    oh[0] = f32x4{0.f,0.f,0.f,0.f};
    oh[1] = f32x4{0.f,0.f,0.f,0.f};

    float pqv[4], c1q[4];
    #pragma unroll
    for (int r = 0; r < 4; ++r) {
        const float pv = pqs[4*g + r];
        pqv[r] = pv;
        c1q[r] = (1.f - pv) * INFV;
    }

    for (int m0 = 0; m0 < NN; m0 += 32) {
        // ---- stage K tile (32x256 bf16) ----
        for (int i = t; i < 32*64; i += 512) {
            const int m = i >> 6, j = i & 63;
            *(bf16x4*)&Ks[m][4*j] = *(const bf16x4*)&Kb[((size_t)b*NN + m0 + m)*ND + 4*j];
        }
        // ---- stage V tile transposed (ALL 32 m), XOR-swizzled m-blocks ----
        // Vst[d][ (m&7) + 8*((m>>3) ^ ((d>>3)&3)) ]
        for (int i = t; i < 1024; i += 512) {
            const int m  = i >> 5;             // 0..31
            const int d0 = (i & 31) * 8;       // 0..248
            const bf16x8 vv = *(const bf16x8*)&Vb[((size_t)b*NN + m0 + m)*ND + d0];
            const int mb = m >> 3, ml = m & 7;
            const int sw = (d0 >> 3) & 3;      // same for all 8 d of this thread
            #pragma unroll
            for (int ee = 0; ee < 8; ++ee) {
                const int e = (ee + (t & 7)) & 7;   // lane-rotated order (bank spread)
                Vst[d0 + e][ml + 8*(mb ^ sw)] = vv[e];
            }
        }
        // ---- stage X_pairs tile (16q x 32m x 3, padded to stride 4) ----
        for (int i = t; i < 1536; i += 512) {
            const int q = i / 96, rem = i - q*96;
            const int m = rem / 3, c = rem - m*3;
            Xps[q*128 + m*4 + c] =
                Xpg[((size_t)(b*NN + q0 + q)*NN + m0)*3 + rem];
        }
        if (t < 32) pks[t] = prk[b*NN + m0 + t];
        __syncthreads();

        // ---- QK^T via MFMA: S[16q x 32m] for this head ----
        f32x4 s[2];
        #pragma unroll
        for (int mg = 0; mg < 2; ++mg) {
            const bf16x8 kf = *(const bf16x8*)&Ks[mg*16 + l16][w*32 + 8*g];
            const f32x4 zero = {0.f,0.f,0.f,0.f};
            s[mg] = mfma16(qf, kf, zero);
        }

        float pk2[2], c1k[2];
        #pragma unroll
        for (int mg = 0; mg < 2; ++mg) {
            const float pv = pks[mg*16 + l16];
            pk2[mg] = pv;
            c1k[mg] = (1.f - pv) * INFV;
        }

        // ---- loc gate + masks, in C-layout: row q = 4g+r, col m = mg*16+l16 ----
        float lv[2][4];
        #pragma unroll
        for (int mg = 0; mg < 2; ++mg) {
            #pragma unroll
            for (int r = 0; r < 4; ++r) {
                const int q = 4*g + r;
                const int m = mg*16 + l16;
                const float4 xv = *(const float4*)&Xps[(q*32 + m)*4];
                float h0 = fmaf(xv.z, g1[2][0], fmaf(xv.y, g1[1][0], fmaf(xv.x, g1[0][0], gb1[0])));
                float h1 = fmaf(xv.z, g1[2][1], fmaf(xv.y, g1[1][1], fmaf(xv.x, g1[0][1], gb1[1])));
                float h2 = fmaf(xv.z, g1[2][2], fmaf(xv.y, g1[1][2], fmaf(xv.x, g1[0][2], gb1[2])));
                h0 = fmaxf(h0, 0.f); h1 = fmaxf(h1, 0.f); h2 = fmaxf(h2, 0.f);
                const float loc = fmaf(h2, g2v[2], fmaf(h1, g2v[1], fmaf(h0, g2v[0], gb2v)));
                float x = fmaf(s[mg][r], 0.0625f, loc);   // content/sqrt(256) + loc
                x = fmaf(pqv[r], x, -c1q[r]);             // query mask
                x = fmaf(pk2[mg], x, -c1k[mg]);           // key mask
                lv[mg][r] = x;
            }
        }

        // ---- online softmax per q-row (16-lane group reductions) ----
        #pragma unroll
        for (int r = 0; r < 4; ++r) {
            float mx = fmaxf(lv[0][r], lv[1][r]);
            mx = fmaxf(mx, __shfl_xor(mx, 1));
            mx = fmaxf(mx, __shfl_xor(mx, 2));
            mx = fmaxf(mx, __shfl_xor(mx, 4));
            mx = fmaxf(mx, __shfl_xor(mx, 8));
            const float mnew = fmaxf(m_run[r], mx);
            const float p0 = __expf(lv[0][r] - mnew);
            const float p1 = __expf(lv[1][r] - mnew);
            Ps[w][4*g + r][l16]      = (bf16)p0;
            Ps[w][4*g + r][16 + l16] = (bf16)p1;
            float ps = p0 + p1;
            ps += __shfl_xor(ps, 1);
            ps += __shfl_xor(ps, 2);
            ps += __shfl_xor(ps, 4);
            ps += __shfl_xor(ps, 8);
            const float corr = __expf(m_run[r] - mnew);
            l_run[r] = l_run[r]*corr + ps;
            m_run[r] = mnew;
            oh[0][r] *= corr;
            oh[1][r] *= corr;
        }

        // ensure wave-local P writes are visible to our own ds_reads
        asm volatile("s_waitcnt lgkmcnt(0)" ::: "memory");
        __builtin_amdgcn_sched_barrier(0);

        // ---- PV via MFMA: Oh += P(16x32) @ V(32x32) ----
        const bf16x8 pf = *(const bf16x8*)&Ps[w][l16][8*g];
        #pragma unroll
        for (int dg = 0; dg < 2; ++dg) {
            const int d = w*32 + dg*16 + l16;
            const int sw = (d >> 3) & 3;
            const bf16x8 vf = *(const bf16x8*)&Vst[d][8*(g ^ sw)];
            oh[dg] = mfma16(pf, vf, oh[dg]);
        }
        __syncthreads();
    }

    // ---- epilogue: O1 = V + Oh / l ----
    #pragma unroll
    for (int r = 0; r < 4; ++r) {
        const float invl = 1.f / l_run[r];
        const int n = q0 + 4*g + r;
        #pragma unroll
        for (int dg = 0; dg < 2; ++dg) {
            const int col = w*32 + dg*16 + l16;
            const size_t idx = ((size_t)b*NN + n)*ND + col;
            O1[idx] = Vf[idx] + oh[dg][r]*invl;
        }
    }
}

extern "C" void kernel_launch(void* const* d_in, const int* in_sizes, int n_in,
                              void* d_out, int out_size, void* d_ws, size_t ws_size,
                              hipStream_t stream)
{
    const float* Y   = (const float*)d_in[1];
    const float* Xp  = (const float*)d_in[2];
    const float* prq = (const float*)d_in[3];
    const float* prk = (const float*)d_in[4];
    const float* Wq  = (const float*)d_in[5];
    const float* bq  = (const float*)d_in[6];
    const float* Wk  = (const float*)d_in[7];
    const float* bk  = (const float*)d_in[8];
    const float* Wv  = (const float*)d_in[9];
    const float* bv  = (const float*)d_in[10];
    const float* Wo  = (const float*)d_in[11];
    const float* bo  = (const float*)d_in[12];
    const float* Wg1 = (const float*)d_in[13];
    const float* bg1 = (const float*)d_in[14];
    const float* wg2 = (const float*)d_in[15];
    const float* bg2 = (const float*)d_in[16];
    float* out = (float*)d_out;

    const size_t BND = (size_t)NB * NN * ND;  // 1M elements
    float* Qf = (float*)d_ws;
    float* Kf = Qf + BND;
    float* Vf = Kf + BND;
    float* O1 = Vf + BND;
    bf16*  Qb = (bf16*)(O1 + BND);
    bf16*  Kb = Qb + BND;
    bf16*  Vb = Kb + BND;
    // ws usage: 4*4MB f32 + 3*2MB bf16 = 22 MB

    // Q,K,V projections (f32 + bf16 copies)
    gemm_k<0><<<dim3(32, 2, 3), 256, 0, stream>>>(
        Y, Wq, bq, Wk, bk, Wv, bv,
        Qf, Qb, Kf, Kb, Vf, Vb, nullptr);

    // fused attention -> O1 = V + Oh
    attn_k<<<dim3(NN/16, NB), 512, 0, stream>>>(
        Qb, Kb, Vb, Vf, Xp, prq, prk, Wg1, bg1, wg2, bg2, O1);

    // O = O1 + relu(O1 @ Wo + bo)
    gemm_k<1><<<dim3(32, 2, 1), 256, 0, stream>>>(
        O1, Wo, bo, Wo, bo, Wo, bo,
        out, nullptr, out, nullptr, out, nullptr, O1);
}

// Round 3
// 126.338 us; speedup vs baseline: 1.7771x; 1.7771x over previous
//
#include <hip/hip_runtime.h>
#include <hip/hip_bf16.h>
#include <math.h>

typedef __bf16 bf16;
typedef __bf16 bf16x4 __attribute__((ext_vector_type(4)));
typedef __bf16 bf16x8 __attribute__((ext_vector_type(8)));
typedef float f32x4 __attribute__((ext_vector_type(4)));

#define NB 4
#define NN 1024
#define ND 256
#define NH 8
#define INFV 1e38f
#define RTHR 8.0f

__device__ __forceinline__ f32x4 mfma16(bf16x8 a, bf16x8 b, f32x4 c) {
    return __builtin_amdgcn_mfma_f32_16x16x32_bf16(a, b, c, 0, 0, 0);
}

// C = A(Mx256) @ W(256x128-tile) + bias.
// MODE0: z<2 -> write bf16 Go; z==2 -> write f32 Fo + transposed bf16 Gt[b][d][n]
// MODE1: out = addsrc + relu(C)
template<int MODE>
__global__ __launch_bounds__(256)
void gemm_k(const float* __restrict__ A,
            const float* __restrict__ W0, const float* __restrict__ b0,
            const float* __restrict__ W1, const float* __restrict__ b1,
            const float* __restrict__ W2, const float* __restrict__ b2,
            float* __restrict__ Fo2, bf16* __restrict__ G0,
            bf16* __restrict__ G1, bf16* __restrict__ Gt,
            float* __restrict__ Fo1, const float* __restrict__ addsrc)
{
    const int z = blockIdx.z;
    const float* W    = (z == 0) ? W0 : (z == 1) ? W1 : W2;
    const float* bias = (z == 0) ? b0 : (z == 1) ? b1 : b2;

    const int brow = blockIdx.x * 128;
    const int bcol = blockIdx.y * 128;
    const int t    = threadIdx.x;
    const int lane = t & 63;
    const int wv   = t >> 6;
    const int g    = lane >> 4;
    const int l16  = lane & 15;

    __shared__ bf16 As[128][40];
    __shared__ bf16 Wt[128][40];

    f32x4 acc[2][8];
    #pragma unroll
    for (int i = 0; i < 2; ++i)
        #pragma unroll
        for (int j = 0; j < 8; ++j) acc[i][j] = f32x4{0.f, 0.f, 0.f, 0.f};

    for (int k0 = 0; k0 < 256; k0 += 32) {
        {
            const int r = t >> 3, j = t & 7;
            #pragma unroll
            for (int p = 0; p < 4; ++p) {
                const float4 v = *(const float4*)&A[(size_t)(brow + r + 32*p)*ND + k0 + 4*j];
                bf16x4 w4 = { (bf16)v.x, (bf16)v.y, (bf16)v.z, (bf16)v.w };
                *(bf16x4*)&As[r + 32*p][4*j] = w4;
            }
        }
        {
            const int c = t & 127, kk = t >> 7;
            #pragma unroll
            for (int p = 0; p < 16; ++p) {
                const int k = kk*16 + p;
                Wt[c][k] = (bf16)W[(size_t)(k0 + k)*ND + bcol + c];
            }
        }
        __syncthreads();

        bf16x8 af[2];
        #pragma unroll
        for (int i = 0; i < 2; ++i)
            af[i] = *(const bf16x8*)&As[wv*32 + i*16 + l16][8*g];
        #pragma unroll
        for (int j = 0; j < 8; ++j) {
            const bf16x8 bfj = *(const bf16x8*)&Wt[j*16 + l16][8*g];
            #pragma unroll
            for (int i = 0; i < 2; ++i) acc[i][j] = mfma16(af[i], bfj, acc[i][j]);
        }
        __syncthreads();
    }

    #pragma unroll
    for (int j = 0; j < 8; ++j) {
        const int col = bcol + j*16 + l16;
        const float bj = bias[col];
        #pragma unroll
        for (int i = 0; i < 2; ++i) {
            const int row0 = brow + wv*32 + i*16 + 4*g;
            if (MODE == 1) {
                #pragma unroll
                for (int r = 0; r < 4; ++r) {
                    const size_t idx = (size_t)(row0 + r)*ND + col;
                    Fo1[idx] = addsrc[idx] + fmaxf(acc[i][j][r] + bj, 0.f);
                }
            } else if (z < 2) {
                bf16* Go = (z == 0) ? G0 : G1;
                #pragma unroll
                for (int r = 0; r < 4; ++r)
                    Go[(size_t)(row0 + r)*ND + col] = (bf16)(acc[i][j][r] + bj);
            } else {
                float vv[4];
                #pragma unroll
                for (int r = 0; r < 4; ++r) {
                    vv[r] = acc[i][j][r] + bj;
                    Fo2[(size_t)(row0 + r)*ND + col] = vv[r];
                }
                const int b2 = row0 >> 10;
                const int n0 = row0 & 1023;
                bf16x4 tv = { (bf16)vv[0], (bf16)vv[1], (bf16)vv[2], (bf16)vv[3] };
                *(bf16x4*)&Gt[((size_t)b2*ND + col)*NN + n0] = tv;
            }
        }
    }
}

// Fused attention, key-split: block = (q-tile 16, batch, z-half of keys), 8 waves = heads.
__global__ __launch_bounds__(512, 4)
void attn_k(const bf16* __restrict__ Qb, const bf16* __restrict__ Kb,
            const bf16* __restrict__ Vt, const float* __restrict__ Xpg,
            const float* __restrict__ prq, const float* __restrict__ prk,
            const float* __restrict__ Wg1, const float* __restrict__ bg1,
            const float* __restrict__ wg2, const float* __restrict__ bg2,
            float* __restrict__ Ohp, float* __restrict__ ml)
{
    const int b    = blockIdx.y;
    const int q0   = blockIdx.x * 16;
    const int z    = blockIdx.z;
    const int mb0  = z * (NN/2);
    const int t    = threadIdx.x;
    const int w    = t >> 6;
    const int lane = t & 63;
    const int g    = lane >> 4;
    const int l16  = lane & 15;

    __shared__ bf16  Ks[32][264];     // [m][d]
    __shared__ bf16  Vst[256][40];    // [d][m] (from pre-transposed Vt)
    __shared__ float Xps[16*132];     // [q][m*4+c], q-stride 132 (528B, breaks 4-way)
    __shared__ bf16  Ps[8][16][40];   // wave-private P

    // head gate weights (uniform per wave)
    float g1[3][3], gb1[3], g2v[3], gb2v;
    #pragma unroll
    for (int c = 0; c < 3; ++c)
        #pragma unroll
        for (int d = 0; d < 3; ++d) g1[c][d] = Wg1[(w*3 + c)*3 + d];
    #pragma unroll
    for (int d = 0; d < 3; ++d) { gb1[d] = bg1[w*3 + d]; g2v[d] = wg2[w*3 + d]; }
    gb2v = bg2[w];

    // Q fragment straight from global (one-time)
    const bf16x8 qf = *(const bf16x8*)&Qb[((size_t)b*NN + q0 + l16)*ND + w*32 + 8*g];

    float pqv[4], c1q[4];
    #pragma unroll
    for (int r = 0; r < 4; ++r) {
        const float pv = prq[b*NN + q0 + 4*g + r];
        pqv[r] = pv;
        c1q[r] = (1.f - pv) * INFV;
    }

    float m_run[4], l_run[4];   // l_run is a per-lane PARTIAL sum (reduced at end)
    f32x4 oh[2];
    #pragma unroll
    for (int r = 0; r < 4; ++r) { m_run[r] = -INFINITY; l_run[r] = 0.f; }
    oh[0] = f32x4{0.f,0.f,0.f,0.f};
    oh[1] = f32x4{0.f,0.f,0.f,0.f};

    for (int it = 0; it < 16; ++it) {
        const int m0 = mb0 + it*32;

        // K stage: 32 rows x 32 octets, b128 conflict-free
        #pragma unroll
        for (int s = 0; s < 2; ++s) {
            const int i = t + s*512;
            const int m = i >> 5, oc = i & 31;
            *(bf16x8*)&Ks[m][8*oc] =
                *(const bf16x8*)&Kb[((size_t)b*NN + m0 + m)*ND + 8*oc];
        }
        // V stage from Vt[b][d][m]: rows of 32 m, b128 writes
        #pragma unroll
        for (int s = 0; s < 2; ++s) {
            const int i = t + s*512;
            const int d = i >> 2, oc = i & 3;
            *(bf16x8*)&Vst[d][8*oc] =
                *(const bf16x8*)&Vt[((size_t)b*ND + d)*NN + m0 + 8*oc];
        }
        // X_pairs stage: 16*32*3 floats
        for (int i = t; i < 1536; i += 512) {
            const int q = i / 96, rem = i - q*96;
            const int m = rem / 3, c = rem - m*3;
            Xps[q*132 + m*4 + c] =
                Xpg[(((size_t)b*NN + q0 + q)*NN + m0)*3 + rem];
        }
        __syncthreads();

        // QK^T
        f32x4 s[2];
        #pragma unroll
        for (int mg = 0; mg < 2; ++mg) {
            const bf16x8 kf = *(const bf16x8*)&Ks[mg*16 + l16][w*32 + 8*g];
            const f32x4 zero = {0.f,0.f,0.f,0.f};
            s[mg] = mfma16(qf, kf, zero);
        }

        float pk2[2], c1k[2];
        #pragma unroll
        for (int mg = 0; mg < 2; ++mg) {
            const float pv = prk[b*NN + m0 + mg*16 + l16];
            pk2[mg] = pv;
            c1k[mg] = (1.f - pv) * INFV;
        }

        // loc gate + masks (C-layout: row q=4g+r, col m=mg*16+l16)
        float lv[2][4];
        #pragma unroll
        for (int mg = 0; mg < 2; ++mg) {
            #pragma unroll
            for (int r = 0; r < 4; ++r) {
                const int q = 4*g + r;
                const int m = mg*16 + l16;
                const float4 xv = *(const float4*)&Xps[q*132 + m*4];
                float h0 = fmaf(xv.z, g1[2][0], fmaf(xv.y, g1[1][0], fmaf(xv.x, g1[0][0], gb1[0])));
                float h1 = fmaf(xv.z, g1[2][1], fmaf(xv.y, g1[1][1], fmaf(xv.x, g1[0][1], gb1[1])));
                float h2 = fmaf(xv.z, g1[2][2], fmaf(xv.y, g1[1][2], fmaf(xv.x, g1[0][2], gb1[2])));
                h0 = fmaxf(h0, 0.f); h1 = fmaxf(h1, 0.f); h2 = fmaxf(h2, 0.f);
                const float loc = fmaf(h2, g2v[2], fmaf(h1, g2v[1], fmaf(h0, g2v[0], gb2v)));
                float x = fmaf(s[mg][r], 0.0625f, loc);
                x = fmaf(pqv[r], x, -c1q[r]);
                x = fmaf(pk2[mg], x, -c1k[mg]);
                lv[mg][r] = x;
            }
        }

        // defer-max online softmax
        float pm[4];
        #pragma unroll
        for (int r = 0; r < 4; ++r) pm[r] = fmaxf(lv[0][r], lv[1][r]);
        const bool cond = (pm[0] <= m_run[0] + RTHR) && (pm[1] <= m_run[1] + RTHR)
                       && (pm[2] <= m_run[2] + RTHR) && (pm[3] <= m_run[3] + RTHR);
        if (!__all((int)cond)) {
            #pragma unroll
            for (int r = 0; r < 4; ++r) {
                float mx = pm[r];
                mx = fmaxf(mx, __shfl_xor(mx, 1));
                mx = fmaxf(mx, __shfl_xor(mx, 2));
                mx = fmaxf(mx, __shfl_xor(mx, 4));
                mx = fmaxf(mx, __shfl_xor(mx, 8));
                const float mnew = fmaxf(m_run[r], mx);
                const float corr = __expf(m_run[r] - mnew);
                l_run[r] *= corr;
                oh[0][r] *= corr;
                oh[1][r] *= corr;
                m_run[r] = mnew;
            }
        }
        #pragma unroll
        for (int r = 0; r < 4; ++r) {
            const float p0 = __expf(lv[0][r] - m_run[r]);
            const float p1 = __expf(lv[1][r] - m_run[r]);
            Ps[w][4*g + r][l16]      = (bf16)p0;
            Ps[w][4*g + r][16 + l16] = (bf16)p1;
            l_run[r] += p0 + p1;
        }

        asm volatile("s_waitcnt lgkmcnt(0)" ::: "memory");
        __builtin_amdgcn_sched_barrier(0);

        // PV
        const bf16x8 pf = *(const bf16x8*)&Ps[w][l16][8*g];
        #pragma unroll
        for (int dg = 0; dg < 2; ++dg) {
            const bf16x8 vf = *(const bf16x8*)&Vst[w*32 + dg*16 + l16][8*g];
            oh[dg] = mfma16(pf, vf, oh[dg]);
        }
        __syncthreads();
    }

    // epilogue: write unnormalized partial oh + (m, l) per row/head
    #pragma unroll
    for (int r = 0; r < 4; ++r) {
        float ls = l_run[r];
        ls += __shfl_xor(ls, 1);
        ls += __shfl_xor(ls, 2);
        ls += __shfl_xor(ls, 4);
        ls += __shfl_xor(ls, 8);
        const int n = q0 + 4*g + r;
        #pragma unroll
        for (int dg = 0; dg < 2; ++dg) {
            const int col = w*32 + dg*16 + l16;
            Ohp[(((size_t)z*NB + b)*NN + n)*ND + col] = oh[dg][r];
        }
        if (l16 == 0) {
            const size_t mi = ((((size_t)z*NB + b)*NN + n)*NH + w)*2;
            ml[mi]   = m_run[r];
            ml[mi+1] = ls;
        }
    }
}

// combine the two key-halves: O1 = Vf + (oh0*w0 + oh1*w1) / (l0*w0 + l1*w1)
__global__ __launch_bounds__(256)
void comb_k(const float* __restrict__ Ohp, const float* __restrict__ ml,
            const float* __restrict__ Vf, float* __restrict__ O1)
{
    const int idx = blockIdx.x * 256 + threadIdx.x;  // 262144 threads, 4 d each
    const int dq = idx & 63;
    const int bn = idx >> 6;          // b*NN + n
    const int d0 = dq * 4;
    const int h  = dq >> 3;

    const size_t i0 = ((size_t)bn*NH + h)*2;
    const size_t i1 = i0 + (size_t)NB*NN*NH*2;
    const float m0 = ml[i0], l0 = ml[i0+1];
    const float m1 = ml[i1], l1 = ml[i1+1];
    const float M  = fmaxf(m0, m1);
    const float w0 = __expf(m0 - M), w1 = __expf(m1 - M);
    const float inv = 1.f / fmaf(l0, w0, l1*w1);

    const size_t e  = (size_t)bn*ND + d0;
    const f32x4 o0 = *(const f32x4*)&Ohp[e];
    const f32x4 o1 = *(const f32x4*)&Ohp[e + (size_t)NB*NN*ND];
    const f32x4 vf = *(const f32x4*)&Vf[e];
    f32x4 out;
    #pragma unroll
    for (int r = 0; r < 4; ++r)
        out[r] = vf[r] + (o0[r]*w0 + o1[r]*w1)*inv;
    *(f32x4*)&O1[e] = out;
}

extern "C" void kernel_launch(void* const* d_in, const int* in_sizes, int n_in,
                              void* d_out, int out_size, void* d_ws, size_t ws_size,
                              hipStream_t stream)
{
    const float* Y   = (const float*)d_in[1];
    const float* Xp  = (const float*)d_in[2];
    const float* prq = (const float*)d_in[3];
    const float* prk = (const float*)d_in[4];
    const float* Wq  = (const float*)d_in[5];
    const float* bq  = (const float*)d_in[6];
    const float* Wk  = (const float*)d_in[7];
    const float* bk  = (const float*)d_in[8];
    const float* Wv  = (const float*)d_in[9];
    const float* bv  = (const float*)d_in[10];
    const float* Wo  = (const float*)d_in[11];
    const float* bo  = (const float*)d_in[12];
    const float* Wg1 = (const float*)d_in[13];
    const float* bg1 = (const float*)d_in[14];
    const float* wg2 = (const float*)d_in[15];
    const float* bg2 = (const float*)d_in[16];
    float* out = (float*)d_out;

    const size_t BND = (size_t)NB * NN * ND;   // 1M
    float* Vf  = (float*)d_ws;                 // 1M f32
    float* Ohp = Vf + BND;                     // 2M f32 (z=0,1)
    float* ml  = Ohp + 2*BND;                  // 131072 f32
    bf16*  Qb  = (bf16*)(ml + (size_t)2*NB*NN*NH*2);  // 1M bf16
    bf16*  Kb  = Qb + BND;                     // 1M bf16
    bf16*  Vt  = Kb + BND;                     // 1M bf16 (transposed [b][d][n])
    float* O1  = (float*)Qb;                   // aliases Qb+Kb (dead after attn)

    gemm_k<0><<<dim3(32, 2, 3), 256, 0, stream>>>(
        Y, Wq, bq, Wk, bk, Wv, bv,
        Vf, Qb, Kb, Vt, nullptr, nullptr);

    attn_k<<<dim3(NN/16, NB, 2), 512, 0, stream>>>(
        Qb, Kb, Vt, Xp, prq, prk, Wg1, bg1, wg2, bg2, Ohp, ml);

    comb_k<<<dim3(1024), 256, 0, stream>>>(Ohp, ml, Vf, O1);

    gemm_k<1><<<dim3(32, 2, 1), 256, 0, stream>>>(
        O1, Wo, bo, Wo, bo, Wo, bo,
        nullptr, nullptr, nullptr, nullptr, out, O1);
}

// Round 4
// 105.806 us; speedup vs baseline: 2.1219x; 1.1941x over previous
//
#include <hip/hip_runtime.h>
#include <hip/hip_bf16.h>
#include <math.h>

typedef __bf16 bf16;
typedef __bf16 bf16x4 __attribute__((ext_vector_type(4)));
typedef __bf16 bf16x8 __attribute__((ext_vector_type(8)));
typedef float f32x4 __attribute__((ext_vector_type(4)));

#define NB 4
#define NN 1024
#define ND 256
#define NH 8
#define INFV 1e38f
#define RTHR 8.0f

__device__ __forceinline__ f32x4 mfma16(bf16x8 a, bf16x8 b, f32x4 c) {
    return __builtin_amdgcn_mfma_f32_16x16x32_bf16(a, b, c, 0, 0, 0);
}

// C = A(Mx256) @ W(256x128-tile) + bias.
// MODE0: z<2 -> write bf16 Go; z==2 -> write f32 Fo + transposed bf16 Gt[b][d][n]
// MODE1: out = addsrc + relu(C)
template<int MODE>
__global__ __launch_bounds__(256)
void gemm_k(const float* __restrict__ A,
            const float* __restrict__ W0, const float* __restrict__ b0,
            const float* __restrict__ W1, const float* __restrict__ b1,
            const float* __restrict__ W2, const float* __restrict__ b2,
            float* __restrict__ Fo2, bf16* __restrict__ G0,
            bf16* __restrict__ G1, bf16* __restrict__ Gt,
            float* __restrict__ Fo1, const float* __restrict__ addsrc)
{
    const int z = blockIdx.z;
    const float* W    = (z == 0) ? W0 : (z == 1) ? W1 : W2;
    const float* bias = (z == 0) ? b0 : (z == 1) ? b1 : b2;

    const int brow = blockIdx.x * 128;
    const int bcol = blockIdx.y * 128;
    const int t    = threadIdx.x;
    const int lane = t & 63;
    const int wv   = t >> 6;
    const int g    = lane >> 4;
    const int l16  = lane & 15;

    __shared__ bf16 As[128][40];
    __shared__ bf16 Wt[128][40];

    f32x4 acc[2][8];
    #pragma unroll
    for (int i = 0; i < 2; ++i)
        #pragma unroll
        for (int j = 0; j < 8; ++j) acc[i][j] = f32x4{0.f, 0.f, 0.f, 0.f};

    for (int k0 = 0; k0 < 256; k0 += 32) {
        {
            const int r = t >> 3, j = t & 7;
            #pragma unroll
            for (int p = 0; p < 4; ++p) {
                const float4 v = *(const float4*)&A[(size_t)(brow + r + 32*p)*ND + k0 + 4*j];
                bf16x4 w4 = { (bf16)v.x, (bf16)v.y, (bf16)v.z, (bf16)v.w };
                *(bf16x4*)&As[r + 32*p][4*j] = w4;
            }
        }
        {
            const int c = t & 127, kk = t >> 7;
            #pragma unroll
            for (int p = 0; p < 16; ++p) {
                const int k = kk*16 + p;
                Wt[c][k] = (bf16)W[(size_t)(k0 + k)*ND + bcol + c];
            }
        }
        __syncthreads();

        bf16x8 af[2];
        #pragma unroll
        for (int i = 0; i < 2; ++i)
            af[i] = *(const bf16x8*)&As[wv*32 + i*16 + l16][8*g];
        #pragma unroll
        for (int j = 0; j < 8; ++j) {
            const bf16x8 bfj = *(const bf16x8*)&Wt[j*16 + l16][8*g];
            #pragma unroll
            for (int i = 0; i < 2; ++i) acc[i][j] = mfma16(af[i], bfj, acc[i][j]);
        }
        __syncthreads();
    }

    #pragma unroll
    for (int j = 0; j < 8; ++j) {
        const int col = bcol + j*16 + l16;
        const float bj = bias[col];
        #pragma unroll
        for (int i = 0; i < 2; ++i) {
            const int row0 = brow + wv*32 + i*16 + 4*g;
            if (MODE == 1) {
                #pragma unroll
                for (int r = 0; r < 4; ++r) {
                    const size_t idx = (size_t)(row0 + r)*ND + col;
                    Fo1[idx] = addsrc[idx] + fmaxf(acc[i][j][r] + bj, 0.f);
                }
            } else if (z < 2) {
                bf16* Go = (z == 0) ? G0 : G1;
                #pragma unroll
                for (int r = 0; r < 4; ++r)
                    Go[(size_t)(row0 + r)*ND + col] = (bf16)(acc[i][j][r] + bj);
            } else {
                float vv[4];
                #pragma unroll
                for (int r = 0; r < 4; ++r) {
                    vv[r] = acc[i][j][r] + bj;
                    Fo2[(size_t)(row0 + r)*ND + col] = vv[r];
                }
                const int b2 = row0 >> 10;
                const int n0 = row0 & 1023;
                bf16x4 tv = { (bf16)vv[0], (bf16)vv[1], (bf16)vv[2], (bf16)vv[3] };
                *(bf16x4*)&Gt[((size_t)b2*ND + col)*NN + n0] = tv;
            }
        }
    }
}

// Fused attention, key-split z=2: block = (16 q-rows, batch, key-half), 8 waves = heads.
// K/V fragments register-prefetched straight from global (per-wave head slice);
// only X_pairs (shared across heads, double-buffered) + P-transpose live in LDS.
__global__ __launch_bounds__(512, 4)
void attn_k(const bf16* __restrict__ Qb, const bf16* __restrict__ Kb,
            const bf16* __restrict__ Vt, const float* __restrict__ Xpg,
            const float* __restrict__ prq, const float* __restrict__ prk,
            const float* __restrict__ Wg1, const float* __restrict__ bg1,
            const float* __restrict__ wg2, const float* __restrict__ bg2,
            float* __restrict__ Ohp, float* __restrict__ ml)
{
    const int b    = blockIdx.y;
    const int q0   = blockIdx.x * 16;
    const int z    = blockIdx.z;
    const int mb0  = z * (NN/2);
    const int t    = threadIdx.x;
    const int w    = t >> 6;
    const int lane = t & 63;
    const int g    = lane >> 4;
    const int l16  = lane & 15;
    const int NT   = 16;

    __shared__ float Xps[2][16*132];   // [q][m*4+c], q-stride 132
    __shared__ bf16  Ps[8][16][40];    // wave-private P

    // head gate weights (uniform per wave)
    float g1[3][3], gb1[3], g2v[3], gb2v;
    #pragma unroll
    for (int c = 0; c < 3; ++c)
        #pragma unroll
        for (int d = 0; d < 3; ++d) g1[c][d] = Wg1[(w*3 + c)*3 + d];
    #pragma unroll
    for (int d = 0; d < 3; ++d) { gb1[d] = bg1[w*3 + d]; g2v[d] = wg2[w*3 + d]; }
    gb2v = bg2[w];

    // Q fragment straight from global (one-time)
    const bf16x8 qf = *(const bf16x8*)&Qb[((size_t)b*NN + q0 + l16)*ND + w*32 + 8*g];

    bool okq[4];
    #pragma unroll
    for (int r = 0; r < 4; ++r)
        okq[r] = prq[b*NN + q0 + 4*g + r] > 0.5f;

    float m_run[4], l_run[4];   // l_run: per-lane partial, reduced at end
    f32x4 oh[2];
    #pragma unroll
    for (int r = 0; r < 4; ++r) { m_run[r] = -INFINITY; l_run[r] = 0.f; }
    oh[0] = f32x4{0.f,0.f,0.f,0.f};
    oh[1] = f32x4{0.f,0.f,0.f,0.f};

    // per-wave global fragment pointers (tile 0)
    const bf16*  kp0 = &Kb[((size_t)b*NN + mb0 + l16)*ND + w*32 + 8*g];
    const bf16*  kp1 = kp0 + (size_t)16*ND;
    const bf16*  vp0 = &Vt[((size_t)b*ND + w*32 + l16)*NN + mb0 + 8*g];
    const bf16*  vp1 = vp0 + (size_t)16*NN;
    const int    xq  = t >> 5, xm = t & 31;
    const float* xpp = &Xpg[(((size_t)b*NN + q0 + xq)*NN + mb0 + xm)*3];
    const float* pkp = &prk[(size_t)b*NN + mb0 + l16];

    // prologue: tile-0 fragments + Xps[0]
    bf16x8 kf0 = *(const bf16x8*)kp0;
    bf16x8 kf1 = *(const bf16x8*)kp1;
    bf16x8 vf0 = *(const bf16x8*)vp0;
    bf16x8 vf1 = *(const bf16x8*)vp1;
    float  xx = xpp[0], xy = xpp[1], xz = xpp[2];
    float  pk0 = pkp[0], pk1 = pkp[16];
    {
        float* dst = &Xps[0][xq*132 + xm*4];
        dst[0] = xx; dst[1] = xy; dst[2] = xz;
    }
    __syncthreads();

    for (int it = 0; it < NT; ++it) {
        const int cur = it & 1;

        // ---- issue next-tile loads (registers; consumed next iter) ----
        bf16x8 kn0, kn1, vn0, vn1;
        float  xnx, xny, xnz, pn0, pn1;
        if (it + 1 < NT) {
            const int off = (it + 1) * 32;
            kn0 = *(const bf16x8*)(kp0 + (size_t)off*ND);
            kn1 = *(const bf16x8*)(kp1 + (size_t)off*ND);
            vn0 = *(const bf16x8*)(vp0 + off);
            vn1 = *(const bf16x8*)(vp1 + off);
            xnx = xpp[(size_t)off*3];
            xny = xpp[(size_t)off*3 + 1];
            xnz = xpp[(size_t)off*3 + 2];
            pn0 = pkp[off]; pn1 = pkp[off + 16];
        }

        // ---- QK^T ----
        const f32x4 zero = {0.f,0.f,0.f,0.f};
        f32x4 s[2];
        s[0] = mfma16(qf, kf0, zero);
        s[1] = mfma16(qf, kf1, zero);

        const bool okk0 = pk0 > 0.5f;
        const bool okk1 = pk1 > 0.5f;

        // ---- loc gate + masks (C-layout: row q=4g+r, col m=mg*16+l16) ----
        float lv[2][4];
        #pragma unroll
        for (int mg = 0; mg < 2; ++mg) {
            const bool okkm = mg ? okk1 : okk0;
            #pragma unroll
            for (int r = 0; r < 4; ++r) {
                const int q = 4*g + r;
                const int m = mg*16 + l16;
                const float4 xv = *(const float4*)&Xps[cur][q*132 + m*4];
                float h0 = fmaf(xv.z, g1[2][0], fmaf(xv.y, g1[1][0], fmaf(xv.x, g1[0][0], gb1[0])));
                float h1 = fmaf(xv.z, g1[2][1], fmaf(xv.y, g1[1][1], fmaf(xv.x, g1[0][1], gb1[1])));
                float h2 = fmaf(xv.z, g1[2][2], fmaf(xv.y, g1[1][2], fmaf(xv.x, g1[0][2], gb1[2])));
                h0 = fmaxf(h0, 0.f); h1 = fmaxf(h1, 0.f); h2 = fmaxf(h2, 0.f);
                const float loc = fmaf(h2, g2v[2], fmaf(h1, g2v[1], fmaf(h0, g2v[0], gb2v)));
                const float y = fmaf(s[mg][r], 0.0625f, loc);
                lv[mg][r] = (okq[r] && okkm) ? y : -INFV;
            }
        }

        // ---- defer-max online softmax ----
        float pm[4];
        #pragma unroll
        for (int r = 0; r < 4; ++r) pm[r] = fmaxf(lv[0][r], lv[1][r]);
        const bool cond = (pm[0] <= m_run[0] + RTHR) && (pm[1] <= m_run[1] + RTHR)
                       && (pm[2] <= m_run[2] + RTHR) && (pm[3] <= m_run[3] + RTHR);
        if (!__all((int)cond)) {
            #pragma unroll
            for (int r = 0; r < 4; ++r) {
                float mx = pm[r];
                mx = fmaxf(mx, __shfl_xor(mx, 1));
                mx = fmaxf(mx, __shfl_xor(mx, 2));
                mx = fmaxf(mx, __shfl_xor(mx, 4));
                mx = fmaxf(mx, __shfl_xor(mx, 8));
                const float mnew = fmaxf(m_run[r], mx);
                const float corr = __expf(m_run[r] - mnew);
                l_run[r] *= corr;
                oh[0][r] *= corr;
                oh[1][r] *= corr;
                m_run[r] = mnew;
            }
        }
        #pragma unroll
        for (int r = 0; r < 4; ++r) {
            const float p0 = __expf(lv[0][r] - m_run[r]);
            const float p1 = __expf(lv[1][r] - m_run[r]);
            Ps[w][4*g + r][l16]      = (bf16)p0;
            Ps[w][4*g + r][16 + l16] = (bf16)p1;
            l_run[r] += p0 + p1;
        }

        // wave-local Ps writes must land before our own ds_read
        asm volatile("s_waitcnt lgkmcnt(0)" ::: "memory");
        __builtin_amdgcn_sched_barrier(0);

        // ---- PV ----
        const bf16x8 pf = *(const bf16x8*)&Ps[w][l16][8*g];
        oh[0] = mfma16(pf, vf0, oh[0]);
        oh[1] = mfma16(pf, vf1, oh[1]);

        // ---- stage next tile into the other Xps buffer; rotate registers ----
        if (it + 1 < NT) {
            float* dst = &Xps[cur ^ 1][xq*132 + xm*4];
            dst[0] = xnx; dst[1] = xny; dst[2] = xnz;
            kf0 = kn0; kf1 = kn1; vf0 = vn0; vf1 = vn1;
            pk0 = pn0; pk1 = pn1;
        }
        __syncthreads();
    }

    // epilogue: unnormalized partial oh + (m, l) per row/head
    #pragma unroll
    for (int r = 0; r < 4; ++r) {
        float ls = l_run[r];
        ls += __shfl_xor(ls, 1);
        ls += __shfl_xor(ls, 2);
        ls += __shfl_xor(ls, 4);
        ls += __shfl_xor(ls, 8);
        const int n = q0 + 4*g + r;
        #pragma unroll
        for (int dg = 0; dg < 2; ++dg) {
            const int col = w*32 + dg*16 + l16;
            Ohp[(((size_t)z*NB + b)*NN + n)*ND + col] = oh[dg][r];
        }
        if (l16 == 0) {
            const size_t mi = ((((size_t)z*NB + b)*NN + n)*NH + w)*2;
            ml[mi]   = m_run[r];
            ml[mi+1] = ls;
        }
    }
}

// combine the two key-halves: O1 = Vf + (oh0*w0 + oh1*w1) / (l0*w0 + l1*w1)
__global__ __launch_bounds__(256)
void comb_k(const float* __restrict__ Ohp, const float* __restrict__ ml,
            const float* __restrict__ Vf, float* __restrict__ O1)
{
    const int idx = blockIdx.x * 256 + threadIdx.x;
    const int dq = idx & 63;
    const int bn = idx >> 6;
    const int d0 = dq * 4;
    const int h  = dq >> 3;

    const size_t i0 = ((size_t)bn*NH + h)*2;
    const size_t i1 = i0 + (size_t)NB*NN*NH*2;
    const float m0 = ml[i0], l0 = ml[i0+1];
    const float m1 = ml[i1], l1 = ml[i1+1];
    const float M  = fmaxf(m0, m1);
    const float w0 = __expf(m0 - M), w1 = __expf(m1 - M);
    const float inv = 1.f / fmaf(l0, w0, l1*w1);

    const size_t e  = (size_t)bn*ND + d0;
    const f32x4 o0 = *(const f32x4*)&Ohp[e];
    const f32x4 o1 = *(const f32x4*)&Ohp[e + (size_t)NB*NN*ND];
    const f32x4 vf = *(const f32x4*)&Vf[e];
    f32x4 out;
    #pragma unroll
    for (int r = 0; r < 4; ++r)
        out[r] = vf[r] + (o0[r]*w0 + o1[r]*w1)*inv;
    *(f32x4*)&O1[e] = out;
}

extern "C" void kernel_launch(void* const* d_in, const int* in_sizes, int n_in,
                              void* d_out, int out_size, void* d_ws, size_t ws_size,
                              hipStream_t stream)
{
    const float* Y   = (const float*)d_in[1];
    const float* Xp  = (const float*)d_in[2];
    const float* prq = (const float*)d_in[3];
    const float* prk = (const float*)d_in[4];
    const float* Wq  = (const float*)d_in[5];
    const float* bq  = (const float*)d_in[6];
    const float* Wk  = (const float*)d_in[7];
    const float* bk  = (const float*)d_in[8];
    const float* Wv  = (const float*)d_in[9];
    const float* bv  = (const float*)d_in[10];
    const float* Wo  = (const float*)d_in[11];
    const float* bo  = (const float*)d_in[12];
    const float* Wg1 = (const float*)d_in[13];
    const float* bg1 = (const float*)d_in[14];
    const float* wg2 = (const float*)d_in[15];
    const float* bg2 = (const float*)d_in[16];
    float* out = (float*)d_out;

    const size_t BND = (size_t)NB * NN * ND;   // 1M
    float* Vf  = (float*)d_ws;                 // 1M f32
    float* Ohp = Vf + BND;                     // 2M f32 (z=0,1)
    float* ml  = Ohp + 2*BND;                  // 131072 f32
    bf16*  Qb  = (bf16*)(ml + (size_t)2*NB*NN*NH*2);  // 1M bf16
    bf16*  Kb  = Qb + BND;                     // 1M bf16
    bf16*  Vt  = Kb + BND;                     // 1M bf16 (transposed [b][d][n])
    float* O1  = (float*)Qb;                   // aliases Qb+Kb (dead after attn)

    gemm_k<0><<<dim3(32, 2, 3), 256, 0, stream>>>(
        Y, Wq, bq, Wk, bk, Wv, bv,
        Vf, Qb, Kb, Vt, nullptr, nullptr);

    attn_k<<<dim3(NN/16, NB, 2), 512, 0, stream>>>(
        Qb, Kb, Vt, Xp, prq, prk, Wg1, bg1, wg2, bg2, Ohp, ml);

    comb_k<<<dim3(1024), 256, 0, stream>>>(Ohp, ml, Vf, O1);

    gemm_k<1><<<dim3(32, 2, 1), 256, 0, stream>>>(
        O1, Wo, bo, Wo, bo, Wo, bo,
        nullptr, nullptr, nullptr, nullptr, out, O1);
}